// Round 1
// baseline (92.026 us; speedup 1.0000x reference)
//
#include <hip/hip_runtime.h>
#include <cmath>

// QuanvolutionSelfAttentionClassifier on MI355X.
//
// Key algebra: softmax over length-1 axis == 1, so attn_weights == mean_embeds
// (rotation/entangle params are dead). With l = c*196 + p and 196 % 4 == 0,
// the embedding index is d = p & 3 = (2h + w) & 3.
//   logits[j] = lin_b[j] + sum_d m[d] * T[d][j]
//   m[d]     = (1/196) * sum_{c, p==d (mod4)} feat[c][p]
//   T[d][j]  = sum_{c, p==d (mod4)} feat[c][p] * lin_w[j, c*196 + p]
// feat[c][p] = conv_b[c] + sum_{kh,kw} x[2h+kh][2w+kw] * conv_w[c,kh,kw]
//
// Mapping: one LANE per sample (logits/softmax lane-local; lin_w reads are
// wave-uniform -> s_load). 4 waves per block split the 14 output rows
// (4/4/4/2); 64 samples per block; 512 blocks. x is transposed sample<->lane
// through a per-wave LDS plane [64][36] (stride 36 -> conflict-free b128
// readback), wave-synchronous (no block barriers in the main loop), with
// register prefetch of the next row pair to overlap HBM latency.

template <int C>
__device__ __forceinline__ float f4c(const float4& v) {
  if constexpr (C == 0) return v.x;
  else if constexpr (C == 1) return v.y;
  else if constexpr (C == 2) return v.z;
  else return v.w;
}

// Accumulate one output-row h (parity PAR = h&1 compile-time so that
// T/msum indices stay static -> registers, never scratch).
template <int PAR>
__device__ __forceinline__ void accum_row(const float4* tr, const float4* br,
                                          const float W[4][4], const float CB[4],
                                          const float* __restrict__ lin_w, int h,
                                          float T[4][10], float msum[4]) {
#pragma unroll
  for (int c = 0; c < 4; ++c) {
    float feat[14];
#pragma unroll
    for (int w = 0; w < 14; ++w) {
      float t0, t1, b0, b1;
      if ((w & 1) == 0) {
        t0 = f4c<0>(tr[w >> 1]); t1 = f4c<1>(tr[w >> 1]);
        b0 = f4c<0>(br[w >> 1]); b1 = f4c<1>(br[w >> 1]);
      } else {
        t0 = f4c<2>(tr[w >> 1]); t1 = f4c<3>(tr[w >> 1]);
        b0 = f4c<2>(br[w >> 1]); b1 = f4c<3>(br[w >> 1]);
      }
      feat[w] = CB[c] + W[c][0] * t0 + W[c][1] * t1 + W[c][2] * b0 + W[c][3] * b1;
    }
#pragma unroll
    for (int w = 0; w < 14; ++w) msum[(w + 2 * PAR) & 3] += feat[w];
#pragma unroll
    for (int j = 0; j < 10; ++j) {
      const float* lwp = lin_w + j * 784 + c * 196 + h * 14;  // uniform -> s_load
#pragma unroll
      for (int w = 0; w < 14; ++w) T[(w + 2 * PAR) & 3][j] += feat[w] * lwp[w];
    }
  }
}

__global__ __launch_bounds__(256, 2) void qsac_kernel(
    const float* __restrict__ x, const float* __restrict__ conv_w,
    const float* __restrict__ conv_b, const float* __restrict__ lin_w,
    const float* __restrict__ lin_b, float* __restrict__ out) {
  __shared__ float smem[4 * 64 * 36];  // 36.9 KB: 4 per-wave planes [64][36]

  const int tid = threadIdx.x;
  const int lane = tid & 63;
  const int wid = __builtin_amdgcn_readfirstlane(tid >> 6);  // force uniform
  const int sbase = blockIdx.x * 64;

  float* plane = smem + wid * (64 * 36);

  // Tiny uniform params -> SGPRs.
  float W[4][4], CB[4];
#pragma unroll
  for (int c = 0; c < 4; ++c) {
    CB[c] = conv_b[c];
#pragma unroll
    for (int t = 0; t < 4; ++t) W[c][t] = conv_w[c * 4 + t];
  }

  float T[4][10];
  float msum[4] = {0.f, 0.f, 0.f, 0.f};
#pragma unroll
  for (int d = 0; d < 4; ++d)
#pragma unroll
    for (int j = 0; j < 10; ++j) T[d][j] = 0.f;

  const int h_lo = wid * 4;
  const int hcnt = (wid == 3) ? 2 : 4;
  const int h_hi = h_lo + hcnt;

  // Hoisted chunk decomposition: chunk cid = k*64+lane -> sample s, col-chunk mm.
  int gbase[7];  // float index of (sample, col-chunk), row added per h
  int wadr[7];   // LDS float offset for the staging write
#pragma unroll
  for (int k = 0; k < 7; ++k) {
    int cid = k * 64 + lane;
    int s = cid / 7;
    int mm = cid - s * 7;
    gbase[k] = (sbase + s) * 784 + mm * 4;
    wadr[k] = s * 36 + mm * 4;
  }

  float4 buf[14];  // prefetch registers: [0..6] top row, [7..13] bottom row
  auto issue = [&](int h, float4* dst) {
#pragma unroll
    for (int k = 0; k < 7; ++k)
      dst[k] = *reinterpret_cast<const float4*>(x + gbase[k] + (2 * h) * 28);
#pragma unroll
    for (int k = 0; k < 7; ++k)
      dst[7 + k] = *reinterpret_cast<const float4*>(x + gbase[k] + (2 * h + 1) * 28);
  };

  issue(h_lo, buf);

#pragma unroll 1
  for (int h = h_lo; h < h_hi; ++h) {
    // Stage top row, read own sample's row back (wave-synchronous: same-wave
    // LDS ops are processed in order; wave_barrier pins compiler ordering).
#pragma unroll
    for (int k = 0; k < 7; ++k)
      *reinterpret_cast<float4*>(plane + wadr[k]) = buf[k];
    __builtin_amdgcn_wave_barrier();
    float4 tr[7];
#pragma unroll
    for (int mm = 0; mm < 7; ++mm)
      tr[mm] = *reinterpret_cast<const float4*>(plane + lane * 36 + mm * 4);
    __builtin_amdgcn_wave_barrier();
    // Stage bottom row into the same plane (WAR safe: in-order LDS pipe).
#pragma unroll
    for (int k = 0; k < 7; ++k)
      *reinterpret_cast<float4*>(plane + wadr[k]) = buf[7 + k];
    __builtin_amdgcn_wave_barrier();
    float4 br[7];
#pragma unroll
    for (int mm = 0; mm < 7; ++mm)
      br[mm] = *reinterpret_cast<const float4*>(plane + lane * 36 + mm * 4);
    __builtin_amdgcn_wave_barrier();

    // Prefetch next row pair while we compute this one.
    if (h + 1 < h_hi) issue(h + 1, buf);

    if (h & 1) accum_row<1>(tr, br, W, CB, lin_w, h, T, msum);
    else       accum_row<0>(tr, br, W, CB, lin_w, h, T, msum);
  }

  // Exchange partial T/msum across the block's waves (overlaps x planes, so
  // barrier first), then wave 0 finishes per-sample epilogue.
  __syncthreads();
  if (wid != 0) {
    float* tex = smem + (wid - 1) * (64 * 44) + lane * 44;
#pragma unroll
    for (int d = 0; d < 4; ++d)
#pragma unroll
      for (int j = 0; j < 10; ++j) tex[d * 10 + j] = T[d][j];
#pragma unroll
    for (int d = 0; d < 4; ++d) tex[40 + d] = msum[d];
  }
  __syncthreads();

  if (wid == 0) {
#pragma unroll
    for (int w2 = 0; w2 < 3; ++w2) {
      const float* tex = smem + w2 * (64 * 44) + lane * 44;
#pragma unroll
      for (int d = 0; d < 4; ++d)
#pragma unroll
        for (int j = 0; j < 10; ++j) T[d][j] += tex[d * 10 + j];
#pragma unroll
      for (int d = 0; d < 4; ++d) msum[d] += tex[40 + d];
    }

    float m[4];
#pragma unroll
    for (int d = 0; d < 4; ++d) m[d] = msum[d] * (1.0f / 196.0f);

    float logits[10];
#pragma unroll
    for (int j = 0; j < 10; ++j) {
      float v = lin_b[j];
#pragma unroll
      for (int d = 0; d < 4; ++d) v += m[d] * T[d][j];
      logits[j] = v;
    }

    float mx = logits[0];
#pragma unroll
    for (int j = 1; j < 10; ++j) mx = fmaxf(mx, logits[j]);
    float se = 0.f;
#pragma unroll
    for (int j = 0; j < 10; ++j) se += __expf(logits[j] - mx);
    const float lse = mx + __logf(se);

    float* op = out + (size_t)(sbase + lane) * 10;
#pragma unroll
    for (int j = 0; j < 10; ++j) op[j] = logits[j] - lse;
  }
}

extern "C" void kernel_launch(void* const* d_in, const int* in_sizes, int n_in,
                              void* d_out, int out_size, void* d_ws, size_t ws_size,
                              hipStream_t stream) {
  (void)n_in; (void)d_ws; (void)ws_size; (void)out_size;
  const float* x = (const float*)d_in[0];
  const float* conv_w = (const float*)d_in[1];
  const float* conv_b = (const float*)d_in[2];
  // d_in[3] (rotation_params) and d_in[4] (entangle_params) are dead:
  // softmax over a length-1 axis is identically 1.
  const float* lin_w = (const float*)d_in[5];
  const float* lin_b = (const float*)d_in[6];
  float* out = (float*)d_out;

  const int B = in_sizes[0] / 784;  // 32768
  const int nblk = B / 64;          // 512 blocks x 256 threads
  hipLaunchKernelGGL(qsac_kernel, dim3(nblk), dim3(256), 0, stream,
                     x, conv_w, conv_b, lin_w, lin_b, out);
}

// Round 2
// 61.384 us; speedup vs baseline: 1.4992x; 1.4992x over previous
//
#include <hip/hip_runtime.h>
#include <cmath>

// QuanvolutionSelfAttentionClassifier on MI355X — round 2.
//
// Algebra: softmax over length-1 axis == 1 -> attn_weights == mean_embeds
// (rotation/entangle params dead). With l = c*196 + p, the embedding index is
// d = p & 3 (since 196 % 4 == 0 and 14h % 4 == 2h).
//   logits[j] = lin_b[j] + sum_d M[d] * T[d][j]
//   M[d]    = a + sum_pix x[pix] * gm(pix)          (a = sum_c conv_b[c] / 4)
//   T[d][j] = cst[d][j] + sum_pix x[pix] * G[pix][j]   (pix restricted to d(pix)==d)
// where for pixel (r,cc): kh=r&1, kw=cc&1, p=(r>>1)*14+(cc>>1), d = p&3,
//   G[pix][j] = sum_c conv_w[c,kh,kw] * lin_w[j, c*196+p]
//   gm(pix)   = (sum_c conv_w[c,kh,kw]) / 196
//   cst[d][j] = sum_{p==d mod 4} sum_c conv_b[c] * lin_w[j, c*196+p]
// Both M and T are linear in x -> main pass is 11 FMAs/pixel into 44 regs.
//
// prep kernel writes G[784][12] + a + cst[40] into d_ws. Main kernel: one LANE
// per sample, 64 samples/block, 4 waves split the 28 x-rows interleaved
// (r = wid + 4i) so the d-rotation parity hpar=(r>>1)&1 == wid>>1 is
// per-wave constant -> single static accumulation path + one post-swap.
// x transposed sample<->lane via per-wave LDS plane [64][36]; A/B register
// double-buffer, 7 manually peeled steps (all-static indexing, no scratch).

#define WS_A    9408
#define WS_CST  9409

__global__ void qsac_prep(const float* __restrict__ cw, const float* __restrict__ cb,
                          const float* __restrict__ lw, float* __restrict__ ws) {
  const int t = blockIdx.x * 98 + threadIdx.x;  // 8 blocks x 98 = 784 pixels
  const int r = t / 28, cc = t - r * 28;
  const int kh = r & 1, kw = cc & 1;
  const int p = (r >> 1) * 14 + (cc >> 1);
  const float w0 = cw[(kh << 1) + kw],      w1 = cw[4 + (kh << 1) + kw],
              w2 = cw[8 + (kh << 1) + kw],  w3 = cw[12 + (kh << 1) + kw];
  float* g = ws + t * 12;
#pragma unroll
  for (int j = 0; j < 10; ++j)
    g[j] = w0 * lw[j * 784 + p]       + w1 * lw[j * 784 + 196 + p] +
           w2 * lw[j * 784 + 392 + p] + w3 * lw[j * 784 + 588 + p];
  g[10] = (w0 + w1 + w2 + w3) * (1.0f / 196.0f);
  g[11] = 0.0f;

  if (blockIdx.x == 0) {
    const int u = threadIdx.x;
    if (u < 40) {
      const int d = u / 10, j = u - (u / 10) * 10;
      const float b0 = cb[0], b1 = cb[1], b2 = cb[2], b3 = cb[3];
      float s = 0.f;
#pragma unroll 7
      for (int q = d; q < 196; q += 4)
        s += b0 * lw[j * 784 + q]       + b1 * lw[j * 784 + 196 + q] +
             b2 * lw[j * 784 + 392 + q] + b3 * lw[j * 784 + 588 + q];
      ws[WS_CST + u] = s;
    } else if (u == 40) {
      ws[WS_A] = (cb[0] + cb[1] + cb[2] + cb[3]) * 0.25f;
    }
  }
}

__device__ __forceinline__ void issue_row(const float* __restrict__ x,
                                          const int (&gbase)[7], int row,
                                          float4 (&dst)[7]) {
#pragma unroll
  for (int k = 0; k < 7; ++k)
    dst[k] = *reinterpret_cast<const float4*>(x + gbase[k] + row * 28);
}

// One pixel: cc = 4*MM+EE (compile-time), dd = (cc>>1)&3 static.
#define QPIX(MM, CMP, EE)                                                   \
  {                                                                         \
    constexpr int cc_ = 4 * (MM) + (EE);                                    \
    constexpr int dd_ = (cc_ >> 1) & 3;                                     \
    const float xv_ = tr[MM].CMP;                                           \
    const float4 g0_ = *reinterpret_cast<const float4*>(Grow + cc_ * 12);   \
    const float4 g1_ = *reinterpret_cast<const float4*>(Grow + cc_ * 12 + 4);\
    const float4 g2_ = *reinterpret_cast<const float4*>(Grow + cc_ * 12 + 8);\
    acc[dd_][0] += xv_ * g0_.x; acc[dd_][1] += xv_ * g0_.y;                 \
    acc[dd_][2] += xv_ * g0_.z; acc[dd_][3] += xv_ * g0_.w;                 \
    acc[dd_][4] += xv_ * g1_.x; acc[dd_][5] += xv_ * g1_.y;                 \
    acc[dd_][6] += xv_ * g1_.z; acc[dd_][7] += xv_ * g1_.w;                 \
    acc[dd_][8] += xv_ * g2_.x; acc[dd_][9] += xv_ * g2_.y;                 \
    mu[dd_]     += xv_ * g2_.z;                                             \
  }

#define QGROUP(MM) QPIX(MM, x, 0) QPIX(MM, y, 1) QPIX(MM, z, 2) QPIX(MM, w, 3)

// One row step: stage BUF->LDS, transpose-read own sample row, optionally
// prefetch row (I+2) back into BUF, accumulate. Wave-synchronous (same-wave
// LDS pipe is in-order; wave_barrier pins compiler ordering).
#define QSTEP(I, BUF, PREF)                                                 \
  {                                                                         \
    _Pragma("unroll") for (int k = 0; k < 7; ++k)                           \
        *reinterpret_cast<float4*>(plane + wadr[k]) = BUF[k];               \
    __builtin_amdgcn_wave_barrier();                                        \
    float4 tr[7];                                                           \
    _Pragma("unroll") for (int mm = 0; mm < 7; ++mm)                        \
        tr[mm] = *reinterpret_cast<const float4*>(plane + lane * 36 + mm * 4);\
    __builtin_amdgcn_wave_barrier();                                        \
    if (PREF) issue_row(x, gbase, wid + 4 * ((I) + 2), BUF);                \
    const float* Grow = Gmat + (wid + 4 * (I)) * 336;                       \
    QGROUP(0) QGROUP(1) QGROUP(2) QGROUP(3) QGROUP(4) QGROUP(5) QGROUP(6)   \
  }

__global__ __launch_bounds__(256, 1) void qsac_main(
    const float* __restrict__ x, const float* __restrict__ ws,
    const float* __restrict__ lin_b, float* __restrict__ out) {
  __shared__ float smem[4 * 64 * 36];  // 36.9 KB: 4 per-wave planes [64][36]

  const int tid = threadIdx.x;
  const int lane = tid & 63;
  const int wid = __builtin_amdgcn_readfirstlane(tid >> 6);
  const int sbase = blockIdx.x * 64;
  float* plane = smem + wid * (64 * 36);
  const float* Gmat = ws;

  // chunk cid = k*64+lane -> sample s, col-chunk mm (4 floats each)
  int gbase[7], wadr[7];
#pragma unroll
  for (int k = 0; k < 7; ++k) {
    const int cid = k * 64 + lane;
    const int s = cid / 7;
    const int mm = cid - s * 7;
    gbase[k] = (sbase + s) * 784 + mm * 4;
    wadr[k] = s * 36 + mm * 4;
  }

  float acc[4][10];
  float mu[4] = {0.f, 0.f, 0.f, 0.f};
#pragma unroll
  for (int d = 0; d < 4; ++d)
#pragma unroll
    for (int j = 0; j < 10; ++j) acc[d][j] = 0.f;

  // Rows for this wave: r = wid + 4*i, i = 0..6. Depth-2 prefetch via A/B.
  float4 A[7], B[7];
  issue_row(x, gbase, wid, A);
  issue_row(x, gbase, wid + 4, B);

  QSTEP(0, A, true)   // consumes row wid+0,  prefetches wid+8  -> A
  QSTEP(1, B, true)   // consumes row wid+4,  prefetches wid+12 -> B
  QSTEP(2, A, true)
  QSTEP(3, B, true)
  QSTEP(4, A, true)
  QSTEP(5, B, false)
  QSTEP(6, A, false)

  // Accumulated with dd = (cc>>1)&3; true d = (dd + 2*hpar)&3, hpar = wid>>1
  // (constant per wave). Fix up with one swap.
  if (wid >> 1) {
#pragma unroll
    for (int j = 0; j < 10; ++j) {
      float t0 = acc[0][j]; acc[0][j] = acc[2][j]; acc[2][j] = t0;
      float t1 = acc[1][j]; acc[1][j] = acc[3][j]; acc[3][j] = t1;
    }
    float t0 = mu[0]; mu[0] = mu[2]; mu[2] = t0;
    float t1 = mu[1]; mu[1] = mu[3]; mu[3] = t1;
  }

  // Cross-wave reduction through LDS (planes are dead now).
  __syncthreads();
  if (wid != 0) {
    float* tex = smem + (wid - 1) * (64 * 44) + lane * 44;
#pragma unroll
    for (int d = 0; d < 4; ++d)
#pragma unroll
      for (int j = 0; j < 10; ++j) tex[d * 10 + j] = acc[d][j];
#pragma unroll
    for (int d = 0; d < 4; ++d) tex[40 + d] = mu[d];
  }
  __syncthreads();

  if (wid == 0) {
#pragma unroll
    for (int w2 = 0; w2 < 3; ++w2) {
      const float* tex = smem + w2 * (64 * 44) + lane * 44;
#pragma unroll
      for (int d = 0; d < 4; ++d)
#pragma unroll
        for (int j = 0; j < 10; ++j) acc[d][j] += tex[d * 10 + j];
#pragma unroll
      for (int d = 0; d < 4; ++d) mu[d] += tex[40 + d];
    }

    const float a = ws[WS_A];
    float m[4];
#pragma unroll
    for (int d = 0; d < 4; ++d) m[d] = a + mu[d];

    float logits[10];
#pragma unroll
    for (int j = 0; j < 10; ++j) {
      float v = lin_b[j];
#pragma unroll
      for (int d = 0; d < 4; ++d) v += m[d] * (ws[WS_CST + d * 10 + j] + acc[d][j]);
      logits[j] = v;
    }

    float mx = logits[0];
#pragma unroll
    for (int j = 1; j < 10; ++j) mx = fmaxf(mx, logits[j]);
    float se = 0.f;
#pragma unroll
    for (int j = 0; j < 10; ++j) se += __expf(logits[j] - mx);
    const float lse = mx + __logf(se);

    float* op = out + (size_t)(sbase + lane) * 10;
#pragma unroll
    for (int j = 0; j < 10; ++j) op[j] = logits[j] - lse;
  }
}

extern "C" void kernel_launch(void* const* d_in, const int* in_sizes, int n_in,
                              void* d_out, int out_size, void* d_ws, size_t ws_size,
                              hipStream_t stream) {
  (void)n_in; (void)ws_size; (void)out_size;
  const float* x = (const float*)d_in[0];
  const float* conv_w = (const float*)d_in[1];
  const float* conv_b = (const float*)d_in[2];
  // d_in[3]/d_in[4] (rotation/entangle) are dead: softmax over length-1 == 1.
  const float* lin_w = (const float*)d_in[5];
  const float* lin_b = (const float*)d_in[6];
  float* out = (float*)d_out;
  float* ws = (float*)d_ws;

  hipLaunchKernelGGL(qsac_prep, dim3(8), dim3(98), 0, stream,
                     conv_w, conv_b, lin_w, ws);

  const int B = in_sizes[0] / 784;  // 32768
  const int nblk = B / 64;          // 512 blocks x 256 threads
  hipLaunchKernelGGL(qsac_main, dim3(nblk), dim3(256), 0, stream,
                     x, ws, lin_b, out);
}